// Round 6
// baseline (372.368 us; speedup 1.0000x reference)
//
#include <hip/hip_runtime.h>

// h0[n][k] = (x[n]==0) ? 0 : emb[x[n]][k]   (padding_idx = 0), float4 per thread
__global__ __launch_bounds__(256) void embed_kernel(
    const int* __restrict__ x, const float* __restrict__ emb,
    float* __restrict__ h0, int n_nodes)
{
    int t = blockIdx.x * 256 + threadIdx.x;
    if (t >= n_nodes * 16) return;
    int n = t >> 4, q = t & 15;
    int xv = x[n];
    float4 v = {0.f, 0.f, 0.f, 0.f};
    if (xv != 0) v = *(const float4*)(emb + (size_t)xv * 64 + q * 4);
    *(float4*)(h0 + (size_t)n * 64 + q * 4) = v;
}

// ---- CSR build: bucket (dst>>7) scatter, then 512-bin (dstlo,rel) sort ----

__global__ __launch_bounds__(256) void bucket_count_kernel(
    const int* __restrict__ ei, int* __restrict__ bucket_count,
    int n_edges, int n_bkt, int per_block)
{
    __shared__ int cnt[512];
    int t = threadIdx.x;
    for (int i = t; i < n_bkt; i += 256) cnt[i] = 0;
    __syncthreads();
    int lo = blockIdx.x * per_block;
    int hi = min(n_edges, lo + per_block);
    for (int e = lo + t; e < hi; e += 256)
        atomicAdd(&cnt[ei[n_edges + e] >> 7], 1);
    __syncthreads();
    for (int i = t; i < n_bkt; i += 256)
        if (cnt[i]) atomicAdd(&bucket_count[i], cnt[i]);
}

__global__ __launch_bounds__(512) void scan_buckets_kernel(
    const int* __restrict__ bucket_count, int* __restrict__ bucket_start,
    int* __restrict__ rowstartR, int n_bkt, int n_edges, int n_nodes)
{
    __shared__ int part[512];
    int t = threadIdx.x;
    part[t] = (t < n_bkt) ? bucket_count[t] : 0;
    __syncthreads();
    for (int off = 1; off < 512; off <<= 1) {
        int v = (t >= off) ? part[t - off] : 0;
        __syncthreads();
        part[t] += v;
        __syncthreads();
    }
    if (t == 0) { bucket_start[0] = 0; rowstartR[4 * n_nodes] = n_edges; }
    if (t < n_bkt) bucket_start[t + 1] = part[t];
}

// 8192 edges/block: reserve a contiguous run per (block,bucket) via one global
// atomic; payload src(16) | r<<16 | dstlo<<18 -> bits 16..24 are the sort key.
__global__ __launch_bounds__(256) void bucket_scatter_kernel(
    const int* __restrict__ ei, const int* __restrict__ et,
    const int* __restrict__ bucket_start, int* __restrict__ bucket_fill,
    int* __restrict__ esort, int n_edges, int n_bkt)
{
    __shared__ int cnt[512], gbase[512], fill2[512];
    const int EPT = 32;
    int t = threadIdx.x;
    int base = blockIdx.x * 256 * EPT;
    for (int i = t; i < n_bkt; i += 256) { cnt[i] = 0; fill2[i] = 0; }
    __syncthreads();
    int pay[EPT], bk[EPT];
#pragma unroll
    for (int i = 0; i < EPT; ++i) {
        int e = base + i * 256 + t;
        bk[i] = -1;
        if (e < n_edges) {
            int s = ei[e], d = ei[n_edges + e], r = et[e];
            int b = d >> 7;
            pay[i] = s | (r << 16) | ((d & 127) << 18);
            bk[i] = b;
            atomicAdd(&cnt[b], 1);
        }
    }
    __syncthreads();
    for (int i = t; i < n_bkt; i += 256)
        if (cnt[i]) gbase[i] = bucket_start[i] + atomicAdd(&bucket_fill[i], cnt[i]);
    __syncthreads();
#pragma unroll
    for (int i = 0; i < EPT; ++i) {
        if (bk[i] >= 0) {
            int pos = gbase[bk[i]] + atomicAdd(&fill2[bk[i]], 1);
            esort[pos] = pay[i];
        }
    }
}

// one block per bucket: 512-bin counting sort (bin = dstlo*4 + r) -> edges
// grouped by (dst, rel); emits rowstartR[dst*4 + r] (r=3 bin = end sentinel).
__global__ __launch_bounds__(256) void bucket_sort_kernel(
    const int* __restrict__ bucket_start, int* __restrict__ esort,
    int* __restrict__ scratch, int* __restrict__ rowstartR, int n_nodes)
{
    __shared__ int cnt[512], off[512], fill[512], ps[256];
    int t = threadIdx.x, b = blockIdx.x;
    int s = bucket_start[b], e = bucket_start[b + 1];
    cnt[t] = 0; cnt[t + 256] = 0; fill[t] = 0; fill[t + 256] = 0;
    __syncthreads();
    int* scr = scratch + (size_t)b * 8192;
    for (int i = s + t; i < e; i += 256) {
        int p = esort[i];
        scr[i - s] = p;
        atomicAdd(&cnt[(p >> 16) & 0x1FF], 1);
    }
    __syncthreads();
    int a0 = cnt[2 * t], a1 = cnt[2 * t + 1];
    ps[t] = a0 + a1;
    __syncthreads();
    for (int o = 1; o < 256; o <<= 1) {
        int v = (t >= o) ? ps[t - o] : 0;
        __syncthreads();
        ps[t] += v;
        __syncthreads();
    }
    int basex = (t > 0) ? ps[t - 1] : 0;
    off[2 * t] = basex;
    off[2 * t + 1] = basex + a0;
    __syncthreads();
    // rowstartR: global index b*512 + bin == (dst*4 + r)
    int d0 = b * 128 + (2 * t >> 2);
    if (d0 < n_nodes) rowstartR[b * 512 + 2 * t] = s + off[2 * t];
    int d1 = b * 128 + ((2 * t + 1) >> 2);
    if (d1 < n_nodes) rowstartR[b * 512 + 2 * t + 1] = s + off[2 * t + 1];
    __syncthreads();
    for (int i = s + t; i < e; i += 256) {
        int p = scr[i - s];
        int bin = (p >> 16) & 0x1FF;
        int pos = s + off[bin] + atomicAdd(&fill[bin], 1);
        esort[pos] = p;
    }
}

// one wave per dst; edges pre-grouped by rel -> 3 mask-free sub-ranges.
// Quarter-wave q strides edges; lane holds channel-quad c. Counts come free
// from range widths (no cnt shuffles); 8 shfl per relation reduction.
__global__ __launch_bounds__(256) void agg_kernel(
    const float* __restrict__ hin, const int* __restrict__ rowstartR,
    const int* __restrict__ esort, float* __restrict__ means, int n_nodes)
{
    int wid = (blockIdx.x * 256 + threadIdx.x) >> 6;
    int lane = threadIdx.x & 63;
    if (wid >= n_nodes) return;
    int q = lane >> 4;       // edge slot within group of 4
    int c = lane & 15;       // channel quad
    int4 rs = *(const int4*)(rowstartR + wid * 4);  // r0 start, r1, r2, end

#pragma unroll
    for (int r = 0; r < 3; ++r) {
        int sR = (r == 0) ? rs.x : (r == 1) ? rs.y : rs.z;
        int eR = (r == 0) ? rs.y : (r == 1) ? rs.z : rs.w;
        float4 a = {0.f, 0.f, 0.f, 0.f};
        for (int i = sR + q; i < eR; i += 4) {
            int p = esort[i];
            float4 v = *(const float4*)(hin + (size_t)(p & 0xFFFF) * 64 + c * 4);
            a.x += v.x; a.y += v.y; a.z += v.z; a.w += v.w;
        }
        a.x += __shfl_xor(a.x, 16); a.y += __shfl_xor(a.y, 16);
        a.z += __shfl_xor(a.z, 16); a.w += __shfl_xor(a.w, 16);
        a.x += __shfl_xor(a.x, 32); a.y += __shfl_xor(a.y, 32);
        a.z += __shfl_xor(a.z, 32); a.w += __shfl_xor(a.w, 32);
        if (q == r) {
            float inv = 1.f / (float)max(eR - sR, 1);
            float4 m = {a.x * inv, a.y * inv, a.z * inv, a.w * inv};
            *(float4*)(means + (size_t)wid * 192 + r * 64 + c * 4) = m;
        }
    }
}

// thread = (8-node octet, j-quad). W[256][64] in LDS; each ds_read_b128 of a
// W row-quad amortized over 8 nodes (32 FMAs) -> LDS ~96 cyc/node, under the
// VALU floor (512 cyc/node-wave).
__global__ __launch_bounds__(256) void transform_kernel(
    const float* __restrict__ hin, const float* __restrict__ means,
    const float* __restrict__ wroot, const float* __restrict__ wrel,
    const float* __restrict__ bias, float* __restrict__ hout, int n_nodes)
{
    __shared__ float wsh[256 * 64];   // 64 KB -> 2 blocks/CU
    int t = threadIdx.x;
    {
        const float4* src = (const float4*)wroot;
        float4* dst = (float4*)wsh;
#pragma unroll
        for (int i = 0; i < 4; ++i) dst[t + i * 256] = src[t + i * 256];
        src = (const float4*)wrel;
        dst = (float4*)(wsh + 4096);
#pragma unroll
        for (int i = 0; i < 12; ++i) dst[t + i * 256] = src[t + i * 256];
    }
    __syncthreads();

    int gt = blockIdx.x * 256 + t;
    int g = gt >> 4, q = gt & 15;
    int n0 = g * 8;
    if (n0 >= n_nodes) return;

    float4 b = *(const float4*)(bias + q * 4);
    float4 acc[8];
#pragma unroll
    for (int i = 0; i < 8; ++i) acc[i] = b;

    const float* hv = hin + (size_t)n0 * 64;
#pragma unroll 2
    for (int k4 = 0; k4 < 16; ++k4) {
        float4 v[8];
#pragma unroll
        for (int i = 0; i < 8; ++i) v[i] = *(const float4*)(hv + i * 64 + k4 * 4);
#pragma unroll
        for (int kk = 0; kk < 4; ++kk) {
            float4 w = *(const float4*)(wsh + (k4 * 4 + kk) * 64 + q * 4);
#pragma unroll
            for (int i = 0; i < 8; ++i) {
                float s = kk == 0 ? v[i].x : kk == 1 ? v[i].y : kk == 2 ? v[i].z : v[i].w;
                acc[i].x = fmaf(s, w.x, acc[i].x);
                acc[i].y = fmaf(s, w.y, acc[i].y);
                acc[i].z = fmaf(s, w.z, acc[i].z);
                acc[i].w = fmaf(s, w.w, acc[i].w);
            }
        }
    }
    const float* mv = means + (size_t)n0 * 192;
#pragma unroll 2
    for (int k4 = 0; k4 < 48; ++k4) {
        float4 v[8];
#pragma unroll
        for (int i = 0; i < 8; ++i) v[i] = *(const float4*)(mv + i * 192 + k4 * 4);
#pragma unroll
        for (int kk = 0; kk < 4; ++kk) {
            float4 w = *(const float4*)(wsh + (64 + k4 * 4 + kk) * 64 + q * 4);
#pragma unroll
            for (int i = 0; i < 8; ++i) {
                float s = kk == 0 ? v[i].x : kk == 1 ? v[i].y : kk == 2 ? v[i].z : v[i].w;
                acc[i].x = fmaf(s, w.x, acc[i].x);
                acc[i].y = fmaf(s, w.y, acc[i].y);
                acc[i].z = fmaf(s, w.z, acc[i].z);
                acc[i].w = fmaf(s, w.w, acc[i].w);
            }
        }
    }
    float* o = hout + (size_t)n0 * 64 + q * 4;
#pragma unroll
    for (int i = 0; i < 8; ++i) {
        float4 r = {fmaxf(acc[i].x, 0.f), fmaxf(acc[i].y, 0.f),
                    fmaxf(acc[i].z, 0.f), fmaxf(acc[i].w, 0.f)};
        *(float4*)(o + i * 64) = r;
    }
}

// wave per graph: batch is sorted -> binary-search bounds, mean, then 64->2 head
__global__ __launch_bounds__(256) void pool_kernel(
    const float* __restrict__ h2, const int* __restrict__ batch,
    const float* __restrict__ linw, const float* __restrict__ linb,
    float* __restrict__ out, int n_nodes, int n_graphs)
{
    int wid = (blockIdx.x * 256 + threadIdx.x) >> 6;
    int lane = threadIdx.x & 63;
    if (wid >= n_graphs) return;
    int g = wid;
    int lo = 0, hi = n_nodes;
    while (lo < hi) { int mid = (lo + hi) >> 1; if (batch[mid] < g) lo = mid + 1; else hi = mid; }
    int s = lo;
    lo = 0; hi = n_nodes;
    while (lo < hi) { int mid = (lo + hi) >> 1; if (batch[mid] < g + 1) lo = mid + 1; else hi = mid; }
    int e = lo;
    float sum = 0.f;
    for (int n = s; n < e; ++n) sum += h2[(size_t)n * 64 + lane];
    float mean = sum / (float)max(e - s, 1);
    float d0 = mean * linw[lane * 2 + 0];
    float d1 = mean * linw[lane * 2 + 1];
    for (int off = 32; off > 0; off >>= 1) {
        d0 += __shfl_down(d0, off);
        d1 += __shfl_down(d1, off);
    }
    if (lane == 0) {
        out[g * 2 + 0] = d0 + linb[0];
        out[g * 2 + 1] = d1 + linb[1];
    }
}

extern "C" void kernel_launch(void* const* d_in, const int* in_sizes, int n_in,
                              void* d_out, int out_size, void* d_ws, size_t ws_size,
                              hipStream_t stream)
{
    const int*   x      = (const int*)d_in[0];
    const int*   ei     = (const int*)d_in[1];
    const int*   et     = (const int*)d_in[2];
    const int*   batch  = (const int*)d_in[3];
    const float* emb    = (const float*)d_in[4];
    const float* w1rel  = (const float*)d_in[5];
    const float* w1root = (const float*)d_in[6];
    const float* b1     = (const float*)d_in[7];
    const float* w2rel  = (const float*)d_in[8];
    const float* w2root = (const float*)d_in[9];
    const float* b2     = (const float*)d_in[10];
    const float* linw   = (const float*)d_in[11];
    const float* linb   = (const float*)d_in[12];
    float* out = (float*)d_out;

    const int N = in_sizes[0];        // 50000
    const int E = in_sizes[2];        // 1250000
    const int G = out_size / 2;       // 512
    const int NBKT = (N + 127) >> 7;  // 391 buckets of 128 dsts

    // workspace layout (~71 MB)
    float* hA        = (float*)d_ws;                     // [N][64]
    float* hB        = hA + (size_t)N * 64;              // [N][64]
    float* means     = hB + (size_t)N * 64;              // [N][192]; head doubles as sort scratch
    int*   esort     = (int*)(means + (size_t)N * 192);  // [E]
    int*   rowstartR = esort + E;                        // [4N+4], 16B-aligned
    int*   bucket_count = rowstartR + 4 * N + 4;         // [512] (zeroed)
    int*   bucket_fill  = bucket_count + 512;            // [512] (zeroed)
    int*   bucket_start = bucket_fill + 512;             // [513]

    hipMemsetAsync(bucket_count, 0, (size_t)1024 * sizeof(int), stream);

    embed_kernel<<<(N * 16 + 255) / 256, 256, 0, stream>>>(x, emb, hA, N);

    int per_block = (E + 255) / 256;
    bucket_count_kernel<<<256, 256, 0, stream>>>(ei, bucket_count, E, NBKT, per_block);
    scan_buckets_kernel<<<1, 512, 0, stream>>>(bucket_count, bucket_start, rowstartR, NBKT, E, N);
    bucket_scatter_kernel<<<(E + 8191) / 8192, 256, 0, stream>>>(ei, et, bucket_start, bucket_fill, esort, E, NBKT);
    bucket_sort_kernel<<<NBKT, 256, 0, stream>>>(bucket_start, esort, (int*)means, rowstartR, N);

    int aggBlocks = (N * 64 + 255) / 256;                 // one wave per dst
    int tfBlocks  = ((N + 7) / 8 * 16 + 255) / 256;       // 8 nodes per thread
    agg_kernel<<<aggBlocks, 256, 0, stream>>>(hA, rowstartR, esort, means, N);
    transform_kernel<<<tfBlocks, 256, 0, stream>>>(hA, means, w1root, w1rel, b1, hB, N);
    agg_kernel<<<aggBlocks, 256, 0, stream>>>(hB, rowstartR, esort, means, N);
    transform_kernel<<<tfBlocks, 256, 0, stream>>>(hB, means, w2root, w2rel, b2, hA, N);

    pool_kernel<<<(G * 64 + 255) / 256, 256, 0, stream>>>(hA, batch, linw, linb, out, N, G);
}